// Round 1
// baseline (1211.518 us; speedup 1.0000x reference)
//
#include <hip/hip_runtime.h>
#include <hip/hip_bf16.h>
#include <math.h>

#define N_NODES 50000
#define N_EDGES 800000
#define N_FEAT 64
#define N_GRAPHS 64
#define N_CLASSES 10

// ---------------- init: deg=1 (self loops), zero pooling buffers ----------------
__global__ void init_k(float* __restrict__ deg, float* __restrict__ sums,
                       float* __restrict__ cnt, int n) {
    int i = blockIdx.x * 256 + threadIdx.x;
    if (i < n) deg[i] = 1.0f;
    if (i < N_GRAPHS * N_FEAT) sums[i] = 0.0f;
    if (i < N_GRAPHS) cnt[i] = 0.0f;
}

// ---------------- edge weights: w=sigmoid(P), deg[col]+=w ----------------
__global__ void edge_w_k(const float* __restrict__ P, const int* __restrict__ col,
                         float* __restrict__ w, float* __restrict__ deg, int E) {
    int e = blockIdx.x * 256 + threadIdx.x;
    if (e < E) {
        float s = 1.0f / (1.0f + expf(-P[e]));
        w[e] = s;
        atomicAdd(&deg[col[e]], s);
    }
}

// ---------------- dis = deg^-0.5 (deg >= 1 always) ----------------
__global__ void dis_k(float* __restrict__ deg, int n) {
    int i = blockIdx.x * 256 + threadIdx.x;
    if (i < n) deg[i] = 1.0f / sqrtf(deg[i]);
}

// ---------------- norm[e] = dis[row]*w*dis[col] (in place over w) ----------------
__global__ void norm_k(const int* __restrict__ row, const int* __restrict__ col,
                       const float* __restrict__ dis, float* __restrict__ w, int E) {
    int e = blockIdx.x * 256 + threadIdx.x;
    if (e < E) w[e] = dis[row[e]] * w[e] * dis[col[e]];
}

// ---------------- dense (n x 64) @ (64 x 64), LDS-staged, 16 rows/block ----------------
__global__ __launch_bounds__(256) void matmul_k(const float* __restrict__ in,
                                                const float* __restrict__ W,
                                                float* __restrict__ out, int n) {
    __shared__ float Wlds[64 * 64];
    __shared__ float Ilds[16 * 64];
    int tid = threadIdx.x;
    for (int i = tid; i < 64 * 64; i += 256) Wlds[i] = W[i];
    int rowBase = blockIdx.x * 16;
    for (int i = tid; i < 16 * 64; i += 256) {
        int r = rowBase + (i >> 6);
        Ilds[i] = (r < n) ? in[r * 64 + (i & 63)] : 0.0f;
    }
    __syncthreads();
    int f = tid & 63;
    int rq = tid >> 6;  // 0..3, handles rows rq*4 .. rq*4+3
    float acc0 = 0.f, acc1 = 0.f, acc2 = 0.f, acc3 = 0.f;
    for (int k = 0; k < 64; ++k) {
        float wv = Wlds[k * 64 + f];
        acc0 += Ilds[(rq * 4 + 0) * 64 + k] * wv;
        acc1 += Ilds[(rq * 4 + 1) * 64 + k] * wv;
        acc2 += Ilds[(rq * 4 + 2) * 64 + k] * wv;
        acc3 += Ilds[(rq * 4 + 3) * 64 + k] * wv;
    }
    float acc[4] = {acc0, acc1, acc2, acc3};
    for (int j = 0; j < 4; ++j) {
        int r = rowBase + rq * 4 + j;
        if (r < n) out[r * 64 + f] = acc[j];
    }
}

// ---------------- agg init with self loop: agg[n][f] = dis[n]^2 * t[n][f] ----------------
__global__ void agg_init_k(const float* __restrict__ t, const float* __restrict__ dis,
                           float* __restrict__ agg, int n) {
    int i = blockIdx.x * 256 + threadIdx.x;
    if (i < n * 64) {
        float d = dis[i >> 6];
        agg[i] = d * d * t[i];
    }
}

// ---------------- scatter: agg[col] += norm[e] * t[row], one wave per edge ----------------
__global__ __launch_bounds__(256) void scatter_k(const int* __restrict__ row,
                                                 const int* __restrict__ col,
                                                 const float* __restrict__ norm,
                                                 const float* __restrict__ t,
                                                 float* __restrict__ agg, int E) {
    int e = blockIdx.x * 4 + (threadIdx.x >> 6);
    if (e >= E) return;
    int lane = threadIdx.x & 63;
    float nv = norm[e];
    int r = row[e], c = col[e];
    atomicAdd(&agg[c * 64 + lane], nv * t[r * 64 + lane]);
}

// ---------------- epilogue: out = (relu?)(in + bias) ----------------
__global__ void bias_act_k(const float* __restrict__ in, const float* __restrict__ b,
                           float* __restrict__ out, int n, int do_relu) {
    int i = blockIdx.x * 256 + threadIdx.x;
    if (i < n * 64) {
        float v = in[i] + b[i & 63];
        if (do_relu) v = fmaxf(v, 0.0f);
        out[i] = v;
    }
}

// ---------------- pooling: sums[batch[n]] += h[n], cnt[batch[n]] += 1 ----------------
__global__ __launch_bounds__(256) void pool_k(const float* __restrict__ h,
                                              const int* __restrict__ batch,
                                              float* __restrict__ sums,
                                              float* __restrict__ cnt, int n) {
    int idx = blockIdx.x * 4 + (threadIdx.x >> 6);
    if (idx >= n) return;
    int lane = threadIdx.x & 63;
    int g = batch[idx];
    atomicAdd(&sums[g * 64 + lane], h[idx * 64 + lane]);
    if (lane == 0) atomicAdd(&cnt[g], 1.0f);
}

// ---------------- classifier: out[g][c] = (sums[g]/cnt[g]) @ Wl + bl ----------------
__global__ void classifier_k(const float* __restrict__ sums, const float* __restrict__ cnt,
                             const float* __restrict__ Wl, const float* __restrict__ bl,
                             float* __restrict__ out) {
    int tid = threadIdx.x;  // 640 threads
    if (tid >= N_GRAPHS * N_CLASSES) return;
    int g = tid / N_CLASSES, c = tid % N_CLASSES;
    float inv = 1.0f / fmaxf(cnt[g], 1.0f);
    float acc = bl[c];
    for (int k = 0; k < 64; ++k)
        acc += sums[g * 64 + k] * inv * Wl[k * N_CLASSES + c];
    out[g * N_CLASSES + c] = acc;
}

extern "C" void kernel_launch(void* const* d_in, const int* in_sizes, int n_in,
                              void* d_out, int out_size, void* d_ws, size_t ws_size,
                              hipStream_t stream) {
    const float* x     = (const float*)d_in[0];
    const int*   eidx  = (const int*)d_in[1];
    const int*   batch = (const int*)d_in[2];
    const float* P     = (const float*)d_in[3];
    const float* W1 = (const float*)d_in[4];
    const float* b1 = (const float*)d_in[5];
    const float* W2 = (const float*)d_in[6];
    const float* b2 = (const float*)d_in[7];
    const float* W3 = (const float*)d_in[8];
    const float* b3 = (const float*)d_in[9];
    const float* Wl = (const float*)d_in[10];
    const float* bl = (const float*)d_in[11];
    float* out = (float*)d_out;

    const int N = in_sizes[2];      // 50000
    const int E = in_sizes[3];      // 800000
    const int* row = eidx;          // edge_index[0]
    const int* col = eidx + E;      // edge_index[1]

    // workspace layout (floats)
    float* ws   = (float*)d_ws;
    float* deg  = ws;                        // N (becomes dis)
    float* nrm  = deg + N;                   // E
    float* bufA = nrm + E;                   // N*64
    float* bufB = bufA + (size_t)N * 64;     // N*64
    float* sums = bufB + (size_t)N * 64;     // 64*64
    float* cnt  = sums + N_GRAPHS * N_FEAT;  // 64

    const int B256 = 256;
    dim3 blk(B256);

    // precompute deg / dis / norm
    init_k<<<(N + 255) / 256, blk, 0, stream>>>(deg, sums, cnt, N);
    edge_w_k<<<(E + 255) / 256, blk, 0, stream>>>(P, col, nrm, deg, E);
    dis_k<<<(N + 255) / 256, blk, 0, stream>>>(deg, N);
    norm_k<<<(E + 255) / 256, blk, 0, stream>>>(row, col, deg, nrm, E);

    int gemm_grid = (N + 15) / 16;
    int elem_grid = (N * 64 + 255) / 256;
    int edge_grid = (E + 3) / 4;
    int pool_grid = (N + 3) / 4;

    // Layer 1: x -> tA -> aggB -> hA (relu)
    matmul_k<<<gemm_grid, blk, 0, stream>>>(x, W1, bufA, N);
    agg_init_k<<<elem_grid, blk, 0, stream>>>(bufA, deg, bufB, N);
    scatter_k<<<edge_grid, blk, 0, stream>>>(row, col, nrm, bufA, bufB, E);
    bias_act_k<<<elem_grid, blk, 0, stream>>>(bufB, b1, bufA, N, 1);

    // Layer 2: hA -> tB -> aggA -> hB (relu)
    matmul_k<<<gemm_grid, blk, 0, stream>>>(bufA, W2, bufB, N);
    agg_init_k<<<elem_grid, blk, 0, stream>>>(bufB, deg, bufA, N);
    scatter_k<<<edge_grid, blk, 0, stream>>>(row, col, nrm, bufB, bufA, E);
    bias_act_k<<<elem_grid, blk, 0, stream>>>(bufA, b2, bufB, N, 1);

    // Layer 3: hB -> tA -> aggB -> hA (no relu)
    matmul_k<<<gemm_grid, blk, 0, stream>>>(bufB, W3, bufA, N);
    agg_init_k<<<elem_grid, blk, 0, stream>>>(bufA, deg, bufB, N);
    scatter_k<<<edge_grid, blk, 0, stream>>>(row, col, nrm, bufA, bufB, E);
    bias_act_k<<<elem_grid, blk, 0, stream>>>(bufB, b3, bufA, N, 0);

    // pooling + classifier
    pool_k<<<pool_grid, blk, 0, stream>>>(bufA, batch, sums, cnt, N);
    classifier_k<<<1, dim3(640), 0, stream>>>(sums, cnt, Wl, bl, out);
}

// Round 2
// 607.827 us; speedup vs baseline: 1.9932x; 1.9932x over previous
//
#include <hip/hip_runtime.h>
#include <hip/hip_bf16.h>
#include <math.h>

#define N_GRAPHS 64
#define N_CLASSES 10

// ---------------- init: deg=1 (self loop weight), edge-count hist = 0 ----------------
__global__ void init_k(float* __restrict__ deg, int* __restrict__ cntE, int n) {
    int i = blockIdx.x * 256 + threadIdx.x;
    if (i < n) { deg[i] = 1.0f; cntE[i] = 0; }
}

// ---------------- w=sigmoid(P); deg[col]+=w; cntE[col]++ ----------------
__global__ void edge_w_k(const float* __restrict__ P, const int* __restrict__ col,
                         float* __restrict__ w, float* __restrict__ deg,
                         int* __restrict__ cntE, int E) {
    int e = blockIdx.x * 256 + threadIdx.x;
    if (e < E) {
        float s = 1.0f / (1.0f + expf(-P[e]));
        w[e] = s;
        int c = col[e];
        atomicAdd(&deg[c], s);
        atomicAdd(&cntE[c], 1);
    }
}

// ---------------- dis = deg^-0.5 (deg >= 1 always due to self loop) ----------------
__global__ void dis_k(float* __restrict__ deg, int n) {
    int i = blockIdx.x * 256 + threadIdx.x;
    if (i < n) deg[i] = 1.0f / sqrtf(deg[i]);
}

// ---------------- scan stage 1: per-block inclusive scan of cntE ----------------
__global__ __launch_bounds__(256) void blockscan_k(const int* __restrict__ cntE,
                                                   int* __restrict__ scanTmp,
                                                   int* __restrict__ partials, int n) {
    __shared__ int sd[256];
    int t = threadIdx.x;
    int i = blockIdx.x * 256 + t;
    int v = (i < n) ? cntE[i] : 0;
    sd[t] = v;
    __syncthreads();
    for (int o = 1; o < 256; o <<= 1) {
        int x = (t >= o) ? sd[t - o] : 0;
        __syncthreads();
        sd[t] += x;
        __syncthreads();
    }
    if (i < n) scanTmp[i] = sd[t];
    if (t == 255) partials[blockIdx.x] = sd[255];
}

// ---------------- scan stage 2: exclusive scan of block partials (NB <= 256) ----------------
__global__ __launch_bounds__(256) void scanpartials_k(int* __restrict__ partials, int nb) {
    __shared__ int sd[256];
    int t = threadIdx.x;
    int v = (t < nb) ? partials[t] : 0;
    sd[t] = v;
    __syncthreads();
    for (int o = 1; o < 256; o <<= 1) {
        int x = (t >= o) ? sd[t - o] : 0;
        __syncthreads();
        sd[t] += x;
        __syncthreads();
    }
    if (t < nb) partials[t] = sd[t] - v;  // exclusive
}

// ---------------- scan stage 3: segStart = inclusive - cnt + blockOffset; cursor=segStart ----------------
__global__ void addback_k(const int* __restrict__ scanTmp, const int* __restrict__ partials,
                          const int* __restrict__ cntE, int* __restrict__ segStart,
                          int* __restrict__ cursor, int n) {
    int i = blockIdx.x * 256 + threadIdx.x;
    if (i < n) {
        int S = scanTmp[i] + partials[i >> 8];
        int st = S - cntE[i];
        segStart[i] = st;
        cursor[i] = st;
    }
}

// ---------------- reorder edges by destination; compute norm on the fly ----------------
__global__ void reorder_k(const int* __restrict__ row, const int* __restrict__ col,
                          const float* __restrict__ w, const float* __restrict__ dis,
                          int* __restrict__ cursor, int* __restrict__ srow,
                          float* __restrict__ snorm, int E) {
    int e = blockIdx.x * 256 + threadIdx.x;
    if (e < E) {
        int r = row[e], c = col[e];
        int p = atomicAdd(&cursor[c], 1);
        srow[p] = r;
        snorm[p] = dis[r] * w[e] * dis[c];
    }
}

// ---------------- dense (n x 64) @ (64 x 64), LDS-staged, 16 rows/block ----------------
__global__ __launch_bounds__(256) void matmul_k(const float* __restrict__ in,
                                                const float* __restrict__ W,
                                                float* __restrict__ out, int n) {
    __shared__ float Wlds[64 * 64];
    __shared__ float Ilds[16 * 64];
    int tid = threadIdx.x;
    for (int i = tid; i < 64 * 64; i += 256) Wlds[i] = W[i];
    int rowBase = blockIdx.x * 16;
    for (int i = tid; i < 16 * 64; i += 256) {
        int r = rowBase + (i >> 6);
        Ilds[i] = (r < n) ? in[r * 64 + (i & 63)] : 0.0f;
    }
    __syncthreads();
    int f = tid & 63;
    int rq = tid >> 6;
    float acc0 = 0.f, acc1 = 0.f, acc2 = 0.f, acc3 = 0.f;
    for (int k = 0; k < 64; ++k) {
        float wv = Wlds[k * 64 + f];
        acc0 += Ilds[(rq * 4 + 0) * 64 + k] * wv;
        acc1 += Ilds[(rq * 4 + 1) * 64 + k] * wv;
        acc2 += Ilds[(rq * 4 + 2) * 64 + k] * wv;
        acc3 += Ilds[(rq * 4 + 3) * 64 + k] * wv;
    }
    float acc[4] = {acc0, acc1, acc2, acc3};
    for (int j = 0; j < 4; ++j) {
        int r = rowBase + rq * 4 + j;
        if (r < n) out[r * 64 + f] = acc[j];
    }
}

// ---------------- fused aggregate: self-loop + CSR gather + bias + relu ----------------
// one wave per destination node; lane = feature
__global__ __launch_bounds__(256) void fused_agg_k(const float* __restrict__ t,
                                                   const int* __restrict__ srow,
                                                   const float* __restrict__ snorm,
                                                   const int* __restrict__ segStart,
                                                   const int* __restrict__ cntE,
                                                   const float* __restrict__ dis,
                                                   const float* __restrict__ b,
                                                   float* __restrict__ out,
                                                   int n, int do_relu) {
    int node = blockIdx.x * 4 + (threadIdx.x >> 6);
    if (node >= n) return;
    int lane = threadIdx.x & 63;
    float d = dis[node];
    float acc = d * d * t[node * 64 + lane];  // self loop (weight 1)
    int start = segStart[node];
    int end = start + cntE[node];
    for (int base = start; base < end; base += 64) {
        int m = end - base; if (m > 64) m = 64;
        int r = 0; float nv = 0.f;
        if (lane < m) { r = srow[base + lane]; nv = snorm[base + lane]; }
        for (int j = 0; j < m; ++j) {
            int rr = __shfl(r, j);
            float nn = __shfl(nv, j);
            acc += nn * t[rr * 64 + lane];
        }
    }
    float v = acc + b[lane];
    if (do_relu) v = fmaxf(v, 0.0f);
    out[node * 64 + lane] = v;
}

// ---------------- fused mean-pool (sorted batch, binary search) + classifier ----------------
__global__ __launch_bounds__(256) void poolclass_k(const float* __restrict__ h,
                                                   const int* __restrict__ batch,
                                                   const float* __restrict__ Wl,
                                                   const float* __restrict__ bl,
                                                   float* __restrict__ out, int n) {
    __shared__ float part[4 * 64];
    __shared__ float pooled[64];
    int g = blockIdx.x;
    int t = threadIdx.x;
    // lower bounds for g and g+1
    int lo = 0, hi = n;
    while (lo < hi) { int m = (lo + hi) >> 1; if (batch[m] < g) lo = m + 1; else hi = m; }
    int start = lo;
    lo = 0; hi = n;
    while (lo < hi) { int m = (lo + hi) >> 1; if (batch[m] < g + 1) lo = m + 1; else hi = m; }
    int end = lo;
    int wave = t >> 6, lane = t & 63;
    float acc = 0.f;
    for (int i = start + wave; i < end; i += 4) acc += h[i * 64 + lane];
    part[wave * 64 + lane] = acc;
    __syncthreads();
    if (t < 64) {
        float s = part[t] + part[64 + t] + part[128 + t] + part[192 + t];
        float cnt = (float)(end - start);
        pooled[t] = s / fmaxf(cnt, 1.0f);
    }
    __syncthreads();
    if (t < N_CLASSES) {
        float accO = bl[t];
        for (int k = 0; k < 64; ++k) accO += pooled[k] * Wl[k * N_CLASSES + t];
        out[g * N_CLASSES + t] = accO;
    }
}

extern "C" void kernel_launch(void* const* d_in, const int* in_sizes, int n_in,
                              void* d_out, int out_size, void* d_ws, size_t ws_size,
                              hipStream_t stream) {
    const float* x     = (const float*)d_in[0];
    const int*   eidx  = (const int*)d_in[1];
    const int*   batch = (const int*)d_in[2];
    const float* P     = (const float*)d_in[3];
    const float* W1 = (const float*)d_in[4];
    const float* b1 = (const float*)d_in[5];
    const float* W2 = (const float*)d_in[6];
    const float* b2 = (const float*)d_in[7];
    const float* W3 = (const float*)d_in[8];
    const float* b3 = (const float*)d_in[9];
    const float* Wl = (const float*)d_in[10];
    const float* bl = (const float*)d_in[11];
    float* out = (float*)d_out;

    const int N = in_sizes[2];      // 50000
    const int E = in_sizes[3];      // 800000
    const int* row = eidx;
    const int* col = eidx + E;

    // workspace layout (all 4-byte elems)
    char* p = (char*)d_ws;
    float* deg      = (float*)p; p += (size_t)N * 4;       // becomes dis
    float* w        = (float*)p; p += (size_t)E * 4;
    int*   cntE     = (int*)p;   p += (size_t)N * 4;
    int*   scanTmp  = (int*)p;   p += (size_t)N * 4;
    int*   segStart = (int*)p;   p += (size_t)N * 4;
    int*   cursor   = (int*)p;   p += (size_t)N * 4;
    int*   partials = (int*)p;   p += 256 * 4;
    int*   srow     = (int*)p;   p += (size_t)E * 4;
    float* snorm    = (float*)p; p += (size_t)E * 4;
    float* bufA     = (float*)p; p += (size_t)N * 64 * 4;
    float* bufB     = (float*)p; p += (size_t)N * 64 * 4;

    dim3 blk(256);
    int nodeG = (N + 255) / 256;       // 196
    int edgeG = (E + 255) / 256;       // 3125
    int NB = nodeG;                    // scan blocks

    init_k<<<nodeG, blk, 0, stream>>>(deg, cntE, N);
    edge_w_k<<<edgeG, blk, 0, stream>>>(P, col, w, deg, cntE, E);
    dis_k<<<nodeG, blk, 0, stream>>>(deg, N);
    blockscan_k<<<NB, blk, 0, stream>>>(cntE, scanTmp, partials, N);
    scanpartials_k<<<1, blk, 0, stream>>>(partials, NB);
    addback_k<<<nodeG, blk, 0, stream>>>(scanTmp, partials, cntE, segStart, cursor, N);
    reorder_k<<<edgeG, blk, 0, stream>>>(row, col, w, deg, cursor, srow, snorm, E);

    int gemmG = (N + 15) / 16;
    int aggG = (N + 3) / 4;

    // Layer 1
    matmul_k<<<gemmG, blk, 0, stream>>>(x, W1, bufA, N);
    fused_agg_k<<<aggG, blk, 0, stream>>>(bufA, srow, snorm, segStart, cntE, deg, b1, bufB, N, 1);
    // Layer 2
    matmul_k<<<gemmG, blk, 0, stream>>>(bufB, W2, bufA, N);
    fused_agg_k<<<aggG, blk, 0, stream>>>(bufA, srow, snorm, segStart, cntE, deg, b2, bufB, N, 1);
    // Layer 3
    matmul_k<<<gemmG, blk, 0, stream>>>(bufB, W3, bufA, N);
    fused_agg_k<<<aggG, blk, 0, stream>>>(bufA, srow, snorm, segStart, cntE, deg, b3, bufB, N, 0);

    // pool + classifier
    poolclass_k<<<N_GRAPHS, blk, 0, stream>>>(bufB, batch, Wl, bl, out, N);
}

// Round 3
// 554.966 us; speedup vs baseline: 2.1830x; 1.0953x over previous
//
#include <hip/hip_runtime.h>
#include <hip/hip_bf16.h>
#include <math.h>

#define N_GRAPHS 64
#define N_CLASSES 10
#define FIXSCALE 1048576.0f  // 2^20 fixed-point scale for packed degree sum

// ---------------- init: zero packed hist ----------------
__global__ void init_k(unsigned long long* __restrict__ packed, int n) {
    int i = blockIdx.x * 256 + threadIdx.x;
    if (i < n) packed[i] = 0ull;
}

// ---------------- one 64-bit atomic per edge: count<<40 | fix(sigmoid(P)) ----------------
__global__ void hist_k(const float* __restrict__ P, const int* __restrict__ col,
                       unsigned long long* __restrict__ packed, int E) {
    int e = blockIdx.x * 256 + threadIdx.x;
    if (e < E) {
        float s = 1.0f / (1.0f + expf(-P[e]));
        unsigned long long v =
            (1ull << 40) | (unsigned long long)(s * FIXSCALE + 0.5f);
        atomicAdd(&packed[col[e]], v);
    }
}

// ---------------- dis = (1 + sum_w)^-0.5 from packed ----------------
__global__ void dis_k(const unsigned long long* __restrict__ packed,
                      float* __restrict__ dis, int n) {
    int i = blockIdx.x * 256 + threadIdx.x;
    if (i < n) {
        float deg = 1.0f + (float)(packed[i] & ((1ull << 40) - 1)) * (1.0f / FIXSCALE);
        dis[i] = 1.0f / sqrtf(deg);
    }
}

// ---------------- scan stage 1: per-block inclusive scan of counts ----------------
__global__ __launch_bounds__(256) void blockscan_k(const unsigned long long* __restrict__ packed,
                                                   int* __restrict__ scanTmp,
                                                   int* __restrict__ partials, int n) {
    __shared__ int sd[256];
    int t = threadIdx.x;
    int i = blockIdx.x * 256 + t;
    int v = (i < n) ? (int)(packed[i] >> 40) : 0;
    sd[t] = v;
    __syncthreads();
    for (int o = 1; o < 256; o <<= 1) {
        int x = (t >= o) ? sd[t - o] : 0;
        __syncthreads();
        sd[t] += x;
        __syncthreads();
    }
    if (i < n) scanTmp[i] = sd[t];
    if (t == 255) partials[blockIdx.x] = sd[255];
}

// ---------------- scan stage 2: exclusive scan of block partials (NB <= 256) ----------------
__global__ __launch_bounds__(256) void scanpartials_k(int* __restrict__ partials, int nb) {
    __shared__ int sd[256];
    int t = threadIdx.x;
    int v = (t < nb) ? partials[t] : 0;
    sd[t] = v;
    __syncthreads();
    for (int o = 1; o < 256; o <<= 1) {
        int x = (t >= o) ? sd[t - o] : 0;
        __syncthreads();
        sd[t] += x;
        __syncthreads();
    }
    if (t < nb) partials[t] = sd[t] - v;  // exclusive
}

// ---------------- scan stage 3: segStart (exclusive), cursor ----------------
__global__ void addback_k(const int* __restrict__ scanTmp, const int* __restrict__ partials,
                          const unsigned long long* __restrict__ packed,
                          int* __restrict__ segStart, int* __restrict__ cursor,
                          int n, int E) {
    int i = blockIdx.x * 256 + threadIdx.x;
    if (i < n) {
        int cnt = (int)(packed[i] >> 40);
        int st = scanTmp[i] + partials[i >> 8] - cnt;
        segStart[i] = st;
        cursor[i] = st;
    }
    if (i == 0) segStart[n] = E;
}

// ---------------- reorder: one packed int2 scattered store per edge ----------------
__global__ void reorder_k(const int* __restrict__ row, const int* __restrict__ col,
                          const float* __restrict__ P, const float* __restrict__ dis,
                          int* __restrict__ cursor, int2* __restrict__ sedge, int E) {
    int e = blockIdx.x * 256 + threadIdx.x;
    if (e < E) {
        int r = row[e], c = col[e];
        float s = 1.0f / (1.0f + expf(-P[e]));
        float nv = dis[r] * s * dis[c];
        int p = atomicAdd(&cursor[c], 1);
        sedge[p] = make_int2(r, __float_as_int(nv));
    }
}

// ---------------- dense (n x 64) @ (64 x 64), LDS-staged, 16 rows/block ----------------
__global__ __launch_bounds__(256) void matmul_k(const float* __restrict__ in,
                                                const float* __restrict__ W,
                                                float* __restrict__ out, int n) {
    __shared__ float Wlds[64 * 64];
    __shared__ float Ilds[16 * 64];
    int tid = threadIdx.x;
    for (int i = tid; i < 64 * 64; i += 256) Wlds[i] = W[i];
    int rowBase = blockIdx.x * 16;
    for (int i = tid; i < 16 * 64; i += 256) {
        int r = rowBase + (i >> 6);
        Ilds[i] = (r < n) ? in[r * 64 + (i & 63)] : 0.0f;
    }
    __syncthreads();
    int f = tid & 63;
    int rq = tid >> 6;
    float acc0 = 0.f, acc1 = 0.f, acc2 = 0.f, acc3 = 0.f;
    for (int k = 0; k < 64; ++k) {
        float wv = Wlds[k * 64 + f];
        acc0 += Ilds[(rq * 4 + 0) * 64 + k] * wv;
        acc1 += Ilds[(rq * 4 + 1) * 64 + k] * wv;
        acc2 += Ilds[(rq * 4 + 2) * 64 + k] * wv;
        acc3 += Ilds[(rq * 4 + 3) * 64 + k] * wv;
    }
    float acc[4] = {acc0, acc1, acc2, acc3};
    for (int j = 0; j < 4; ++j) {
        int r = rowBase + rq * 4 + j;
        if (r < n) out[r * 64 + f] = acc[j];
    }
}

// ---------------- fused aggregate: self-loop + CSR gather + bias + relu ----------------
// one wave per destination node; lane = feature
__global__ __launch_bounds__(256) void fused_agg_k(const float* __restrict__ t,
                                                   const int2* __restrict__ sedge,
                                                   const int* __restrict__ segStart,
                                                   const float* __restrict__ dis,
                                                   const float* __restrict__ b,
                                                   float* __restrict__ out,
                                                   int n, int do_relu) {
    int node = blockIdx.x * 4 + (threadIdx.x >> 6);
    if (node >= n) return;
    int lane = threadIdx.x & 63;
    float d = dis[node];
    float acc = d * d * t[node * 64 + lane];  // self loop (weight 1)
    int start = segStart[node];
    int end = segStart[node + 1];
    for (int base = start; base < end; base += 64) {
        int m = end - base; if (m > 64) m = 64;
        int2 ed = make_int2(0, 0);
        if (lane < m) ed = sedge[base + lane];
        for (int j = 0; j < m; ++j) {
            int rr = __shfl(ed.x, j);
            float nn = __int_as_float(__shfl(ed.y, j));
            acc += nn * t[rr * 64 + lane];
        }
    }
    float v = acc + b[lane];
    if (do_relu) v = fmaxf(v, 0.0f);
    out[node * 64 + lane] = v;
}

// ---------------- fused mean-pool (sorted batch, binary search) + classifier ----------------
__global__ __launch_bounds__(256) void poolclass_k(const float* __restrict__ h,
                                                   const int* __restrict__ batch,
                                                   const float* __restrict__ Wl,
                                                   const float* __restrict__ bl,
                                                   float* __restrict__ out, int n) {
    __shared__ float part[4 * 64];
    __shared__ float pooled[64];
    int g = blockIdx.x;
    int t = threadIdx.x;
    int lo = 0, hi = n;
    while (lo < hi) { int m = (lo + hi) >> 1; if (batch[m] < g) lo = m + 1; else hi = m; }
    int start = lo;
    lo = 0; hi = n;
    while (lo < hi) { int m = (lo + hi) >> 1; if (batch[m] < g + 1) lo = m + 1; else hi = m; }
    int end = lo;
    int wave = t >> 6, lane = t & 63;
    float acc = 0.f;
    for (int i = start + wave; i < end; i += 4) acc += h[i * 64 + lane];
    part[wave * 64 + lane] = acc;
    __syncthreads();
    if (t < 64) {
        float s = part[t] + part[64 + t] + part[128 + t] + part[192 + t];
        float cnt = (float)(end - start);
        pooled[t] = s / fmaxf(cnt, 1.0f);
    }
    __syncthreads();
    if (t < N_CLASSES) {
        float accO = bl[t];
        for (int k = 0; k < 64; ++k) accO += pooled[k] * Wl[k * N_CLASSES + t];
        out[g * N_CLASSES + t] = accO;
    }
}

extern "C" void kernel_launch(void* const* d_in, const int* in_sizes, int n_in,
                              void* d_out, int out_size, void* d_ws, size_t ws_size,
                              hipStream_t stream) {
    const float* x     = (const float*)d_in[0];
    const int*   eidx  = (const int*)d_in[1];
    const int*   batch = (const int*)d_in[2];
    const float* P     = (const float*)d_in[3];
    const float* W1 = (const float*)d_in[4];
    const float* b1 = (const float*)d_in[5];
    const float* W2 = (const float*)d_in[6];
    const float* b2 = (const float*)d_in[7];
    const float* W3 = (const float*)d_in[8];
    const float* b3 = (const float*)d_in[9];
    const float* Wl = (const float*)d_in[10];
    const float* bl = (const float*)d_in[11];
    float* out = (float*)d_out;

    const int N = in_sizes[2];      // 50000
    const int E = in_sizes[3];      // 800000
    const int* row = eidx;
    const int* col = eidx + E;

    // workspace layout
    char* p = (char*)d_ws;
    unsigned long long* packed = (unsigned long long*)p; p += (size_t)N * 8;
    float* dis      = (float*)p; p += (size_t)N * 4;
    int*   scanTmp  = (int*)p;   p += (size_t)N * 4;
    int*   segStart = (int*)p;   p += (size_t)(N + 1) * 4;
    int*   cursor   = (int*)p;   p += (size_t)N * 4;
    int*   partials = (int*)p;   p += 256 * 4;
    int2*  sedge    = (int2*)p;  p += (size_t)E * 8;
    float* bufA     = (float*)p; p += (size_t)N * 64 * 4;
    float* bufB     = (float*)p; p += (size_t)N * 64 * 4;

    dim3 blk(256);
    int nodeG = (N + 255) / 256;       // 196
    int edgeG = (E + 255) / 256;       // 3125
    int NB = nodeG;

    init_k<<<nodeG, blk, 0, stream>>>(packed, N);
    hist_k<<<edgeG, blk, 0, stream>>>(P, col, packed, E);
    dis_k<<<nodeG, blk, 0, stream>>>(packed, dis, N);
    blockscan_k<<<NB, blk, 0, stream>>>(packed, scanTmp, partials, N);
    scanpartials_k<<<1, blk, 0, stream>>>(partials, NB);
    addback_k<<<nodeG, blk, 0, stream>>>(scanTmp, partials, packed, segStart, cursor, N, E);
    reorder_k<<<edgeG, blk, 0, stream>>>(row, col, P, dis, cursor, sedge, E);

    int gemmG = (N + 15) / 16;
    int aggG = (N + 3) / 4;

    // Layer 1
    matmul_k<<<gemmG, blk, 0, stream>>>(x, W1, bufA, N);
    fused_agg_k<<<aggG, blk, 0, stream>>>(bufA, sedge, segStart, dis, b1, bufB, N, 1);
    // Layer 2
    matmul_k<<<gemmG, blk, 0, stream>>>(bufB, W2, bufA, N);
    fused_agg_k<<<aggG, blk, 0, stream>>>(bufA, sedge, segStart, dis, b2, bufB, N, 1);
    // Layer 3
    matmul_k<<<gemmG, blk, 0, stream>>>(bufB, W3, bufA, N);
    fused_agg_k<<<aggG, blk, 0, stream>>>(bufA, sedge, segStart, dis, b3, bufB, N, 0);

    // pool + classifier
    poolclass_k<<<N_GRAPHS, blk, 0, stream>>>(bufB, batch, Wl, bl, out, N);
}

// Round 4
// 515.389 us; speedup vs baseline: 2.3507x; 1.0768x over previous
//
#include <hip/hip_runtime.h>
#include <hip/hip_bf16.h>
#include <math.h>

#define N_GRAPHS 64
#define N_CLASSES 10
#define FIXSCALE 1048576.0f  // 2^20 fixed-point scale for packed degree sum

// ---------------- init: zero packed hist + pooling buffers ----------------
__global__ void init_k(unsigned long long* __restrict__ packed,
                       float* __restrict__ sums, float* __restrict__ cntG, int n) {
    int i = blockIdx.x * 256 + threadIdx.x;
    if (i < n) packed[i] = 0ull;
    if (i < N_GRAPHS * 64) sums[i] = 0.0f;
    if (i < N_GRAPHS) cntG[i] = 0.0f;
}

// ---------------- one 64-bit atomic per edge: count<<40 | fix(sigmoid(P)) ----------------
__global__ void hist_k(const float* __restrict__ P, const int* __restrict__ col,
                       unsigned long long* __restrict__ packed, int E) {
    int e = blockIdx.x * 256 + threadIdx.x;
    if (e < E) {
        float s = 1.0f / (1.0f + expf(-P[e]));
        unsigned long long v =
            (1ull << 40) | (unsigned long long)(s * FIXSCALE + 0.5f);
        atomicAdd(&packed[col[e]], v);
    }
}

// ---------------- dis = (1 + sum_w)^-0.5 from packed ----------------
__global__ void dis_k(const unsigned long long* __restrict__ packed,
                      float* __restrict__ dis, int n) {
    int i = blockIdx.x * 256 + threadIdx.x;
    if (i < n) {
        float deg = 1.0f + (float)(packed[i] & ((1ull << 40) - 1)) * (1.0f / FIXSCALE);
        dis[i] = 1.0f / sqrtf(deg);
    }
}

// ---------------- scan stage 1: per-block inclusive scan of counts ----------------
__global__ __launch_bounds__(256) void blockscan_k(const unsigned long long* __restrict__ packed,
                                                   int* __restrict__ scanTmp,
                                                   int* __restrict__ partials, int n) {
    __shared__ int sd[256];
    int t = threadIdx.x;
    int i = blockIdx.x * 256 + t;
    int v = (i < n) ? (int)(packed[i] >> 40) : 0;
    sd[t] = v;
    __syncthreads();
    for (int o = 1; o < 256; o <<= 1) {
        int x = (t >= o) ? sd[t - o] : 0;
        __syncthreads();
        sd[t] += x;
        __syncthreads();
    }
    if (i < n) scanTmp[i] = sd[t];
    if (t == 255) partials[blockIdx.x] = sd[255];
}

// ---------------- scan stage 2: exclusive scan of block partials (NB <= 256) ----------------
__global__ __launch_bounds__(256) void scanpartials_k(int* __restrict__ partials, int nb) {
    __shared__ int sd[256];
    int t = threadIdx.x;
    int v = (t < nb) ? partials[t] : 0;
    sd[t] = v;
    __syncthreads();
    for (int o = 1; o < 256; o <<= 1) {
        int x = (t >= o) ? sd[t - o] : 0;
        __syncthreads();
        sd[t] += x;
        __syncthreads();
    }
    if (t < nb) partials[t] = sd[t] - v;  // exclusive
}

// ---------------- scan stage 3: segStart (exclusive), cursor ----------------
__global__ void addback_k(const int* __restrict__ scanTmp, const int* __restrict__ partials,
                          const unsigned long long* __restrict__ packed,
                          int* __restrict__ segStart, int* __restrict__ cursor,
                          int n, int E) {
    int i = blockIdx.x * 256 + threadIdx.x;
    if (i < n) {
        int cnt = (int)(packed[i] >> 40);
        int st = scanTmp[i] + partials[i >> 8] - cnt;
        segStart[i] = st;
        cursor[i] = st;
    }
    if (i == 0) segStart[n] = E;
}

// ---------------- reorder: one packed int2 scattered store per edge ----------------
__global__ void reorder_k(const int* __restrict__ row, const int* __restrict__ col,
                          const float* __restrict__ P, const float* __restrict__ dis,
                          int* __restrict__ cursor, int2* __restrict__ sedge, int E) {
    int e = blockIdx.x * 256 + threadIdx.x;
    if (e < E) {
        int r = row[e], c = col[e];
        float s = 1.0f / (1.0f + expf(-P[e]));
        float nv = dis[r] * s * dis[c];
        int p = atomicAdd(&cursor[c], 1);
        sedge[p] = make_int2(r, __float_as_int(nv));
    }
}

// ---------------- dense (n x 64) @ (64 x 64), LDS-staged, 16 rows/block ----------------
__global__ __launch_bounds__(256) void matmul_k(const float* __restrict__ in,
                                                const float* __restrict__ W,
                                                float* __restrict__ out, int n) {
    __shared__ float Wlds[64 * 64];
    __shared__ float Ilds[16 * 64];
    int tid = threadIdx.x;
    for (int i = tid; i < 64 * 64; i += 256) Wlds[i] = W[i];
    int rowBase = blockIdx.x * 16;
    for (int i = tid; i < 16 * 64; i += 256) {
        int r = rowBase + (i >> 6);
        Ilds[i] = (r < n) ? in[r * 64 + (i & 63)] : 0.0f;
    }
    __syncthreads();
    int f = tid & 63;
    int rq = tid >> 6;
    float acc0 = 0.f, acc1 = 0.f, acc2 = 0.f, acc3 = 0.f;
    for (int k = 0; k < 64; ++k) {
        float wv = Wlds[k * 64 + f];
        acc0 += Ilds[(rq * 4 + 0) * 64 + k] * wv;
        acc1 += Ilds[(rq * 4 + 1) * 64 + k] * wv;
        acc2 += Ilds[(rq * 4 + 2) * 64 + k] * wv;
        acc3 += Ilds[(rq * 4 + 3) * 64 + k] * wv;
    }
    float acc[4] = {acc0, acc1, acc2, acc3};
    for (int j = 0; j < 4; ++j) {
        int r = rowBase + rq * 4 + j;
        if (r < n) out[r * 64 + f] = acc[j];
    }
}

// ---------------- fused aggregate: self-loop + CSR gather + bias + relu ----------------
__global__ __launch_bounds__(256) void fused_agg_k(const float* __restrict__ t,
                                                   const int2* __restrict__ sedge,
                                                   const int* __restrict__ segStart,
                                                   const float* __restrict__ dis,
                                                   const float* __restrict__ b,
                                                   float* __restrict__ out,
                                                   int n, int do_relu) {
    int node = blockIdx.x * 4 + (threadIdx.x >> 6);
    if (node >= n) return;
    int lane = threadIdx.x & 63;
    float d = dis[node];
    float acc = d * d * t[node * 64 + lane];  // self loop (weight 1)
    int start = segStart[node];
    int end = segStart[node + 1];
    for (int base = start; base < end; base += 64) {
        int m = end - base; if (m > 64) m = 64;
        int2 ed = make_int2(0, 0);
        if (lane < m) ed = sedge[base + lane];
        for (int j = 0; j < m; ++j) {
            int rr = __shfl(ed.x, j);
            float nn = __int_as_float(__shfl(ed.y, j));
            acc += nn * t[rr * 64 + lane];
        }
    }
    float v = acc + b[lane];
    if (do_relu) v = fmaxf(v, 0.0f);
    out[node * 64 + lane] = v;
}

// ---------------- pooling phase A: segmented partial sums, flush on graph change ----------------
// 4 waves/block, each wave reduces a contiguous 32-node run; lane = feature
__global__ __launch_bounds__(256) void poolpart_k(const float* __restrict__ h,
                                                  const int* __restrict__ batch,
                                                  float* __restrict__ sums,
                                                  float* __restrict__ cntG, int n) {
    int wave = threadIdx.x >> 6, lane = threadIdx.x & 63;
    int base = blockIdx.x * 128 + wave * 32;
    if (base >= n) return;
    int end = base + 32; if (end > n) end = n;
    int g = batch[base];
    float acc = 0.0f;
    int run = 0;
    for (int i = base; i < end; ++i) {
        int gi = batch[i];
        if (gi != g) {
            atomicAdd(&sums[g * 64 + lane], acc);
            if (lane == 0) atomicAdd(&cntG[g], (float)run);
            g = gi; acc = 0.0f; run = 0;
        }
        acc += h[i * 64 + lane];
        ++run;
    }
    atomicAdd(&sums[g * 64 + lane], acc);
    if (lane == 0) atomicAdd(&cntG[g], (float)run);
}

// ---------------- pooling phase B: divide + classifier ----------------
__global__ void classify_k(const float* __restrict__ sums, const float* __restrict__ cntG,
                           const float* __restrict__ Wl, const float* __restrict__ bl,
                           float* __restrict__ out) {
    __shared__ float pooled[64];
    int g = blockIdx.x;
    int t = threadIdx.x;  // 64
    float inv = 1.0f / fmaxf(cntG[g], 1.0f);
    pooled[t] = sums[g * 64 + t] * inv;
    __syncthreads();
    if (t < N_CLASSES) {
        float acc = bl[t];
        for (int k = 0; k < 64; ++k) acc += pooled[k] * Wl[k * N_CLASSES + t];
        out[g * N_CLASSES + t] = acc;
    }
}

extern "C" void kernel_launch(void* const* d_in, const int* in_sizes, int n_in,
                              void* d_out, int out_size, void* d_ws, size_t ws_size,
                              hipStream_t stream) {
    const float* x     = (const float*)d_in[0];
    const int*   eidx  = (const int*)d_in[1];
    const int*   batch = (const int*)d_in[2];
    const float* P     = (const float*)d_in[3];
    const float* W1 = (const float*)d_in[4];
    const float* b1 = (const float*)d_in[5];
    const float* W2 = (const float*)d_in[6];
    const float* b2 = (const float*)d_in[7];
    const float* W3 = (const float*)d_in[8];
    const float* b3 = (const float*)d_in[9];
    const float* Wl = (const float*)d_in[10];
    const float* bl = (const float*)d_in[11];
    float* out = (float*)d_out;

    const int N = in_sizes[2];      // 50000
    const int E = in_sizes[3];      // 800000
    const int* row = eidx;
    const int* col = eidx + E;

    // workspace layout
    char* p = (char*)d_ws;
    unsigned long long* packed = (unsigned long long*)p; p += (size_t)N * 8;
    float* dis      = (float*)p; p += (size_t)N * 4;
    int*   scanTmp  = (int*)p;   p += (size_t)N * 4;
    int*   segStart = (int*)p;   p += (size_t)(N + 1) * 4;
    int*   cursor   = (int*)p;   p += (size_t)N * 4;
    int*   partials = (int*)p;   p += 256 * 4;
    float* sums     = (float*)p; p += (size_t)N_GRAPHS * 64 * 4;
    float* cntG     = (float*)p; p += (size_t)N_GRAPHS * 4;
    int2*  sedge    = (int2*)p;  p += (size_t)E * 8;
    float* bufA     = (float*)p; p += (size_t)N * 64 * 4;
    float* bufB     = (float*)p; p += (size_t)N * 64 * 4;

    dim3 blk(256);
    int nodeG = (N + 255) / 256;       // 196
    int edgeG = (E + 255) / 256;       // 3125
    int NB = nodeG;

    init_k<<<nodeG, blk, 0, stream>>>(packed, sums, cntG, N);
    hist_k<<<edgeG, blk, 0, stream>>>(P, col, packed, E);
    dis_k<<<nodeG, blk, 0, stream>>>(packed, dis, N);
    blockscan_k<<<NB, blk, 0, stream>>>(packed, scanTmp, partials, N);
    scanpartials_k<<<1, blk, 0, stream>>>(partials, NB);
    addback_k<<<nodeG, blk, 0, stream>>>(scanTmp, partials, packed, segStart, cursor, N, E);
    reorder_k<<<edgeG, blk, 0, stream>>>(row, col, P, dis, cursor, sedge, E);

    int gemmG = (N + 15) / 16;
    int aggG = (N + 3) / 4;

    // Layer 1
    matmul_k<<<gemmG, blk, 0, stream>>>(x, W1, bufA, N);
    fused_agg_k<<<aggG, blk, 0, stream>>>(bufA, sedge, segStart, dis, b1, bufB, N, 1);
    // Layer 2
    matmul_k<<<gemmG, blk, 0, stream>>>(bufB, W2, bufA, N);
    fused_agg_k<<<aggG, blk, 0, stream>>>(bufA, sedge, segStart, dis, b2, bufB, N, 1);
    // Layer 3
    matmul_k<<<gemmG, blk, 0, stream>>>(bufB, W3, bufA, N);
    fused_agg_k<<<aggG, blk, 0, stream>>>(bufA, sedge, segStart, dis, b3, bufB, N, 0);

    // pool phase A + classifier
    int poolG = (N + 127) / 128;
    poolpart_k<<<poolG, blk, 0, stream>>>(bufB, batch, sums, cntG, N);
    classify_k<<<N_GRAPHS, dim3(64), 0, stream>>>(sums, cntG, Wl, bl, out);
}

// Round 6
// 480.174 us; speedup vs baseline: 2.5231x; 1.0733x over previous
//
#include <hip/hip_runtime.h>
#include <hip/hip_bf16.h>
#include <math.h>

#define N_GRAPHS 64
#define N_CLASSES 10
#define FIXSCALE 1048576.0f  // 2^20 fixed-point scale for packed degree sum

// ---------------- init: zero packed hist + pooling buffers ----------------
__global__ void init_k(unsigned long long* __restrict__ packed,
                       float* __restrict__ sums, float* __restrict__ cntG, int n) {
    int i = blockIdx.x * 256 + threadIdx.x;
    if (i < n) packed[i] = 0ull;
    if (i < N_GRAPHS * 64) sums[i] = 0.0f;
    if (i < N_GRAPHS) cntG[i] = 0.0f;
}

// ---------------- one 64-bit atomic per edge: count<<40 | fix(sigmoid(P)) ----------------
__global__ void hist_k(const float* __restrict__ P, const int* __restrict__ col,
                       unsigned long long* __restrict__ packed, int E) {
    int e = blockIdx.x * 256 + threadIdx.x;
    if (e < E) {
        float s = 1.0f / (1.0f + expf(-P[e]));
        unsigned long long v =
            (1ull << 40) | (unsigned long long)(s * FIXSCALE + 0.5f);
        atomicAdd(&packed[col[e]], v);
    }
}

// ---------------- dis = (1 + sum_w)^-0.5 from packed ----------------
__global__ void dis_k(const unsigned long long* __restrict__ packed,
                      float* __restrict__ dis, int n) {
    int i = blockIdx.x * 256 + threadIdx.x;
    if (i < n) {
        float deg = 1.0f + (float)(packed[i] & ((1ull << 40) - 1)) * (1.0f / FIXSCALE);
        dis[i] = 1.0f / sqrtf(deg);
    }
}

// ---------------- scan stage 1: per-block inclusive scan of counts ----------------
__global__ __launch_bounds__(256) void blockscan_k(const unsigned long long* __restrict__ packed,
                                                   int* __restrict__ scanTmp,
                                                   int* __restrict__ partials, int n) {
    __shared__ int sd[256];
    int t = threadIdx.x;
    int i = blockIdx.x * 256 + t;
    int v = (i < n) ? (int)(packed[i] >> 40) : 0;
    sd[t] = v;
    __syncthreads();
    for (int o = 1; o < 256; o <<= 1) {
        int x = (t >= o) ? sd[t - o] : 0;
        __syncthreads();
        sd[t] += x;
        __syncthreads();
    }
    if (i < n) scanTmp[i] = sd[t];
    if (t == 255) partials[blockIdx.x] = sd[255];
}

// ---------------- scan stage 2: exclusive scan of block partials (NB <= 256) ----------------
__global__ __launch_bounds__(256) void scanpartials_k(int* __restrict__ partials, int nb) {
    __shared__ int sd[256];
    int t = threadIdx.x;
    int v = (t < nb) ? partials[t] : 0;
    sd[t] = v;
    __syncthreads();
    for (int o = 1; o < 256; o <<= 1) {
        int x = (t >= o) ? sd[t - o] : 0;
        __syncthreads();
        sd[t] += x;
        __syncthreads();
    }
    if (t < nb) partials[t] = sd[t] - v;  // exclusive
}

// ---------------- scan stage 3: segStart (exclusive), cursor ----------------
__global__ void addback_k(const int* __restrict__ scanTmp, const int* __restrict__ partials,
                          const unsigned long long* __restrict__ packed,
                          int* __restrict__ segStart, int* __restrict__ cursor,
                          int n, int E) {
    int i = blockIdx.x * 256 + threadIdx.x;
    if (i < n) {
        int cnt = (int)(packed[i] >> 40);
        int st = scanTmp[i] + partials[i >> 8] - cnt;
        segStart[i] = st;
        cursor[i] = st;
    }
    if (i == 0) segStart[n] = E;
}

// ---------------- reorder: one packed int2 scattered store per edge ----------------
__global__ void reorder_k(const int* __restrict__ row, const int* __restrict__ col,
                          const float* __restrict__ P, const float* __restrict__ dis,
                          int* __restrict__ cursor, int2* __restrict__ sedge, int E) {
    int e = blockIdx.x * 256 + threadIdx.x;
    if (e < E) {
        int r = row[e], c = col[e];
        float s = 1.0f / (1.0f + expf(-P[e]));
        float nv = dis[r] * s * dis[c];
        int p = atomicAdd(&cursor[c], 1);
        sedge[p] = make_int2(r, __float_as_int(nv));
    }
}

// ---------------- fold tail linear ops: Wc = W3 @ Wl, bc = b3 @ Wl + bl ----------------
// NOTE: needs 64*N_CLASSES = 640 threads -> launch with 3 blocks of 256!
__global__ void fold_k(const float* __restrict__ W3, const float* __restrict__ b3,
                       const float* __restrict__ Wl, const float* __restrict__ bl,
                       float* __restrict__ Wc, float* __restrict__ bc) {
    int t = blockIdx.x * 256 + threadIdx.x;
    if (t < 64 * N_CLASSES) {
        int k = t / N_CLASSES, c = t % N_CLASSES;
        float acc = 0.0f;
        for (int m = 0; m < 64; ++m) acc += W3[k * 64 + m] * Wl[m * N_CLASSES + c];
        Wc[t] = acc;
    }
    if (t < N_CLASSES) {
        float acc = bl[t];
        for (int m = 0; m < 64; ++m) acc += b3[m] * Wl[m * N_CLASSES + t];
        bc[t] = acc;
    }
}

// ---------------- fused layer: agg (self-loop + CSR gather) -> [@W + b -> relu] ----------------
// uses agg(h@W) == agg(h)@W; one wave per 8 nodes; lane = feature.
// MODE 1: matmul + bias + relu.  MODE 0: pure aggregation (tail folded elsewhere).
template <int MODE>
__global__ __launch_bounds__(256) void agg_mm_k(const float* __restrict__ h,
                                                const int2* __restrict__ sedge,
                                                const int* __restrict__ segStart,
                                                const float* __restrict__ dis,
                                                const float* __restrict__ W,
                                                const float* __restrict__ b,
                                                float* __restrict__ out, int n) {
    int wid = blockIdx.x * 4 + (threadIdx.x >> 6);
    int lane = threadIdx.x & 63;

    float Wcol[64];
    float bv = 0.0f;
    if (MODE == 1) {
        bv = b[lane];
#pragma unroll
        for (int k = 0; k < 64; ++k) Wcol[k] = W[k * 64 + lane];  // column `lane` of W
    }

    int nodeBase = wid * 8;
    for (int i = 0; i < 8; ++i) {
        int node = nodeBase + i;
        if (node >= n) return;
        float d = dis[node];
        float acc = d * d * h[node * 64 + lane];  // self loop (weight 1)
        int start = segStart[node];
        int end = segStart[node + 1];
        for (int base = start; base < end; base += 64) {
            int m = end - base; if (m > 64) m = 64;
            int2 ed = make_int2(0, 0);
            if (lane < m) ed = sedge[base + lane];
            for (int j = 0; j < m; ++j) {
                int rr = __shfl(ed.x, j);
                float nn = __int_as_float(__shfl(ed.y, j));
                acc += nn * h[rr * 64 + lane];
            }
        }
        if (MODE == 1) {
            float o = bv;
#pragma unroll
            for (int k = 0; k < 64; ++k) {
                float av = __int_as_float(__builtin_amdgcn_readlane(__float_as_int(acc), k));
                o = fmaf(av, Wcol[k], o);
            }
            o = fmaxf(o, 0.0f);
            out[node * 64 + lane] = o;
        } else {
            out[node * 64 + lane] = acc;
        }
    }
}

// ---------------- pooling phase A: segmented partial sums, flush on graph change ----------------
__global__ __launch_bounds__(256) void poolpart_k(const float* __restrict__ h,
                                                  const int* __restrict__ batch,
                                                  float* __restrict__ sums,
                                                  float* __restrict__ cntG, int n) {
    int wave = threadIdx.x >> 6, lane = threadIdx.x & 63;
    int base = blockIdx.x * 128 + wave * 32;
    if (base >= n) return;
    int end = base + 32; if (end > n) end = n;
    int g = batch[base];
    float acc = 0.0f;
    int run = 0;
    for (int i = base; i < end; ++i) {
        int gi = batch[i];
        if (gi != g) {
            atomicAdd(&sums[g * 64 + lane], acc);
            if (lane == 0) atomicAdd(&cntG[g], (float)run);
            g = gi; acc = 0.0f; run = 0;
        }
        acc += h[i * 64 + lane];
        ++run;
    }
    atomicAdd(&sums[g * 64 + lane], acc);
    if (lane == 0) atomicAdd(&cntG[g], (float)run);
}

// ---------------- pooling phase B: mean + folded classifier (Wc, bc) ----------------
__global__ void classify_k(const float* __restrict__ sums, const float* __restrict__ cntG,
                           const float* __restrict__ Wc, const float* __restrict__ bc,
                           float* __restrict__ out) {
    __shared__ float pooled[64];
    int g = blockIdx.x;
    int t = threadIdx.x;  // 64
    float inv = 1.0f / fmaxf(cntG[g], 1.0f);
    pooled[t] = sums[g * 64 + t] * inv;
    __syncthreads();
    if (t < N_CLASSES) {
        float acc = bc[t];
        for (int k = 0; k < 64; ++k) acc += pooled[k] * Wc[k * N_CLASSES + t];
        out[g * N_CLASSES + t] = acc;
    }
}

extern "C" void kernel_launch(void* const* d_in, const int* in_sizes, int n_in,
                              void* d_out, int out_size, void* d_ws, size_t ws_size,
                              hipStream_t stream) {
    const float* x     = (const float*)d_in[0];
    const int*   eidx  = (const int*)d_in[1];
    const int*   batch = (const int*)d_in[2];
    const float* P     = (const float*)d_in[3];
    const float* W1 = (const float*)d_in[4];
    const float* b1 = (const float*)d_in[5];
    const float* W2 = (const float*)d_in[6];
    const float* b2 = (const float*)d_in[7];
    const float* W3 = (const float*)d_in[8];
    const float* b3 = (const float*)d_in[9];
    const float* Wl = (const float*)d_in[10];
    const float* bl = (const float*)d_in[11];
    float* out = (float*)d_out;

    const int N = in_sizes[2];      // 50000
    const int E = in_sizes[3];      // 800000
    const int* row = eidx;
    const int* col = eidx + E;

    // workspace layout
    char* p = (char*)d_ws;
    unsigned long long* packed = (unsigned long long*)p; p += (size_t)N * 8;
    float* dis      = (float*)p; p += (size_t)N * 4;
    int*   scanTmp  = (int*)p;   p += (size_t)N * 4;
    int*   segStart = (int*)p;   p += (size_t)(N + 1) * 4;
    int*   cursor   = (int*)p;   p += (size_t)N * 4;
    int*   partials = (int*)p;   p += 256 * 4;
    float* sums     = (float*)p; p += (size_t)N_GRAPHS * 64 * 4;
    float* cntG     = (float*)p; p += (size_t)N_GRAPHS * 4;
    float* Wc       = (float*)p; p += (size_t)64 * N_CLASSES * 4;
    float* bc       = (float*)p; p += (size_t)N_CLASSES * 4;
    int2*  sedge    = (int2*)p;  p += (size_t)E * 8;
    float* bufA     = (float*)p; p += (size_t)N * 64 * 4;
    float* bufB     = (float*)p; p += (size_t)N * 64 * 4;

    dim3 blk(256);
    int nodeG = (N + 255) / 256;       // 196
    int edgeG = (E + 255) / 256;       // 3125
    int NB = nodeG;

    init_k<<<nodeG, blk, 0, stream>>>(packed, sums, cntG, N);
    hist_k<<<edgeG, blk, 0, stream>>>(P, col, packed, E);
    dis_k<<<nodeG, blk, 0, stream>>>(packed, dis, N);
    blockscan_k<<<NB, blk, 0, stream>>>(packed, scanTmp, partials, N);
    scanpartials_k<<<1, blk, 0, stream>>>(partials, NB);
    addback_k<<<nodeG, blk, 0, stream>>>(scanTmp, partials, packed, segStart, cursor, N, E);
    reorder_k<<<edgeG, blk, 0, stream>>>(row, col, P, dis, cursor, sedge, E);
    fold_k<<<(64 * N_CLASSES + 255) / 256, blk, 0, stream>>>(W3, b3, Wl, bl, Wc, bc);

    int aggG = (N + 31) / 32;  // 8 nodes/wave, 4 waves/block

    // Layer 1: h1 = relu(agg(x) @ W1 + b1)
    agg_mm_k<1><<<aggG, blk, 0, stream>>>(x, sedge, segStart, dis, W1, b1, bufA, N);
    // Layer 2: h2 = relu(agg(h1) @ W2 + b2)
    agg_mm_k<1><<<aggG, blk, 0, stream>>>(bufA, sedge, segStart, dis, W2, b2, bufB, N);
    // Layer 3 (pure agg; W3/b3 folded into classifier)
    agg_mm_k<0><<<aggG, blk, 0, stream>>>(bufB, sedge, segStart, dis, nullptr, nullptr, bufA, N);

    // pool + folded classifier
    int poolG = (N + 127) / 128;
    poolpart_k<<<poolG, blk, 0, stream>>>(bufA, batch, sums, cntG, N);
    classify_k<<<N_GRAPHS, dim3(64), 0, stream>>>(sums, cntG, Wc, bc, out);
}